// Round 16
// baseline (593.843 us; speedup 1.0000x reference)
//
#include <hip/hip_runtime.h>
#include <hip/hip_bf16.h>
#include <hip/hip_cooperative_groups.h>

namespace cg = cooperative_groups;

#define B_ 4
#define N_ 2048
#define D_ 1024
#define H_ 8
#define HD_ 128

typedef __attribute__((ext_vector_type(4))) float f32x4;
typedef __attribute__((ext_vector_type(8))) short bf16x8;

__device__ __forceinline__ short f2bf(float f) {
    unsigned u = __builtin_bit_cast(unsigned, f);
    u = (u + 0x7FFFu + ((u >> 16) & 1u)) >> 16;   // round-to-nearest-even
    return (short)u;
}
__device__ __forceinline__ float bf2f(unsigned short s) {
    unsigned u = (unsigned)s << 16;
    return __builtin_bit_cast(float, u);
}

typedef const __attribute__((address_space(1))) void* gas_t;
typedef __attribute__((address_space(3))) void* las_t;

__device__ __forceinline__ void gload16(const void* g, void* l) {
    __builtin_amdgcn_global_load_lds((gas_t)g, (las_t)l, 16, 0, 0);
}

// ===========================================================================
// Shared phase bodies (used by both the fused kernel and the fallback path)
// ===========================================================================

__device__ __forceinline__ void cvt_unit(
    const float* __restrict__ h, short* __restrict__ hb,
    const float* __restrict__ Wr, short* __restrict__ wrb, int u, int tid)
{
    const float* src;
    short* dst;
    int i;
    if (u < 4096) { src = h;  dst = hb;  i = u * 256 + tid; }
    else          { src = Wr; dst = wrb; i = (u - 4096) * 256 + tid; }
    float4 a = ((const float4*)src)[i * 2];
    float4 b = ((const float4*)src)[i * 2 + 1];
    bf16x8 o;
    o[0] = f2bf(a.x); o[1] = f2bf(a.y); o[2] = f2bf(a.z); o[3] = f2bf(a.w);
    o[4] = f2bf(b.x); o[5] = f2bf(b.y); o[6] = f2bf(b.z); o[7] = f2bf(b.w);
    ((bf16x8*)dst)[i] = o;
}

// proj: 64x128 tile, BK=32, gload16 staging, 2 barriers/step (measured
// optimum ~26us/660TF; direct-reg 92us, 32-row tile 49us).
__device__ __forceinline__ void proj_body(
    const short* __restrict__ hb, const short* __restrict__ wrb,
    const float* __restrict__ att_r, float* __restrict__ sr,
    short* sA, short* sB, float (*part)[64],
    int rowBase, int head, int tid)
{
    const int lane = tid & 63;
    const int wave = tid >> 6;
    const int cc   = lane & 15;
    const int g    = lane >> 4;

    const int srow = lane >> 2;
    const int scol = (lane & 3) * 8;
    const short* gA0 = hb  + (size_t)(rowBase + wave * 16 + srow) * D_ + scol;
    const short* gB0 = wrb + (size_t)(head * HD_ + wave * 32 + srow) * D_ + scol;
    const short* gB1 = gB0 + (size_t)16 * D_;
    char* lA = (char*)sA + wave * 1024;
    char* lB = (char*)sB + wave * 2048;

    f32x4 acc[4][2];
#pragma unroll
    for (int m = 0; m < 4; ++m)
#pragma unroll
        for (int n = 0; n < 2; ++n) acc[m][n] = (f32x4){0.f, 0.f, 0.f, 0.f};

    for (int k0 = 0; k0 < D_; k0 += 32) {
        gload16(gA0 + k0, lA);
        gload16(gB0 + k0, lB);
        gload16(gB1 + k0, lB + 1024);
        __syncthreads();

        bf16x8 aF[4], bF[2];
#pragma unroll
        for (int m = 0; m < 4; ++m)
            aF[m] = *(const bf16x8*)(sA + (m * 16 + cc) * 32 + g * 8);
#pragma unroll
        for (int n = 0; n < 2; ++n)
            bF[n] = *(const bf16x8*)(sB + (wave * 32 + n * 16 + cc) * 32 + g * 8);
#pragma unroll
        for (int m = 0; m < 4; ++m)
#pragma unroll
            for (int n = 0; n < 2; ++n)
                acc[m][n] = __builtin_amdgcn_mfma_f32_16x16x32_bf16(
                    aF[m], bF[n], acc[m][n], 0, 0, 0);
        __syncthreads();
    }

    float ar[2];
#pragma unroll
    for (int n = 0; n < 2; ++n) ar[n] = att_r[wave * 32 + n * 16 + cc];

#pragma unroll
    for (int m = 0; m < 4; ++m) {
#pragma unroll
        for (int r = 0; r < 4; ++r) {
            float p = 0.f;
#pragma unroll
            for (int n = 0; n < 2; ++n) {
                float v = acc[m][n][r];
                v = v > 0.f ? v : 0.01f * v;    // leaky
                p += v * ar[n];
            }
            p += __shfl_xor(p, 1); p += __shfl_xor(p, 2);
            p += __shfl_xor(p, 4); p += __shfl_xor(p, 8);
            if (cc == 0) part[wave][m * 16 + g * 4 + r] = p;
        }
    }
    __syncthreads();
    if (tid < 64) {
        const int grow = rowBase + tid;
        const int b = grow >> 11, j = grow & (N_ - 1);
        sr[(size_t)(b * H_ + head) * N_ + j] =
            part[0][tid] + part[1][tid] + part[2][tid] + part[3][tid];
    }
}

// hbar with inline softmax stats (L2-resident sr)
__device__ __forceinline__ void hbar_body(
    const short* __restrict__ hbm, const float* __restrict__ sr,
    float* __restrict__ hp, float* smx, float* sism, float (*wl)[128],
    int dc, int jc, int b, int tid)
{
    const int d = dc * 256 + tid;
    {
        const int hh = tid >> 5;
        const int sl = tid & 31;
        const float4* row = (const float4*)(sr + (size_t)(b * H_ + hh) * N_);
        float4 v[16];
        float mx = -1e30f;
#pragma unroll
        for (int k = 0; k < 16; ++k) {
            v[k] = row[sl + k * 32];
            mx = fmaxf(fmaxf(mx, fmaxf(v[k].x, v[k].y)), fmaxf(v[k].z, v[k].w));
        }
#pragma unroll
        for (int m = 1; m < 32; m <<= 1) mx = fmaxf(mx, __shfl_xor(mx, m));
        float sum = 0.f;
#pragma unroll
        for (int k = 0; k < 16; ++k)
            sum += expf(v[k].x - mx) + expf(v[k].y - mx) +
                   expf(v[k].z - mx) + expf(v[k].w - mx);
#pragma unroll
        for (int m = 1; m < 32; m <<= 1) sum += __shfl_xor(sum, m);
        if (sl == 0) { smx[hh] = mx; sism[hh] = 1.f / sum; }
    }
    __syncthreads();

    for (int idx = tid; idx < 1024; idx += 256) {
        const int hh = idx >> 7, jj = idx & 127;
        wl[hh][jj] = expf(sr[(size_t)(b * H_ + hh) * N_ + jc * 128 + jj]
                          - smx[hh]) * sism[hh];
    }
    __syncthreads();

    float acc[8] = {0.f, 0.f, 0.f, 0.f, 0.f, 0.f, 0.f, 0.f};
    const short* hp0 = hbm + ((size_t)(b * N_ + jc * 128)) * D_ + d;
    for (int jj = 0; jj < 128; ++jj) {
        float hv = bf2f((unsigned short)hp0[(size_t)jj * D_]);
#pragma unroll
        for (int hh = 0; hh < 8; ++hh) acc[hh] += wl[hh][jj] * hv;
    }
#pragma unroll
    for (int hh = 0; hh < 8; ++hh)
        hp[((size_t)(jc * 32) + b * 8 + hh) * D_ + d] = acc[hh];
}

__device__ __forceinline__ void ctx_body(
    const float* __restrict__ hp, const float* __restrict__ Wr,
    float* __restrict__ ctx, float* xs, int bid, int tid)
{
    const int bh = bid >> 5;
    const int b = bh >> 3, head = bh & 7;
    const int dg = (bid & 31) * 4;
    const int lane = tid & 63, wave = tid >> 6;

    float4 s = {0.f, 0.f, 0.f, 0.f};
#pragma unroll
    for (int jc = 0; jc < 16; ++jc) {
        float4 v = ((const float4*)(hp + ((size_t)(jc * 32) + bh) * D_))[tid];
        s.x += v.x; s.y += v.y; s.z += v.z; s.w += v.w;
    }
    ((float4*)xs)[tid] = s;
    __syncthreads();

    const int o = dg + wave;
    const float* wrow = Wr + (size_t)(head * HD_ + o) * D_;
    float acc = 0.f;
#pragma unroll
    for (int it = 0; it < 4; ++it) {
        float4 wv = *(const float4*)(wrow + it * 256 + lane * 4);
        float4 xv = ((const float4*)xs)[it * 64 + lane];
        acc += wv.x * xv.x + wv.y * xv.y + wv.z * xv.z + wv.w * xv.w;
    }
#pragma unroll
    for (int m = 1; m < 64; m <<= 1) acc += __shfl_xor(acc, m);
    if (lane == 0) ctx[(size_t)b * D_ + head * HD_ + o] = acc;
    __syncthreads();
}

__device__ __forceinline__ void fvec_body(
    const float* __restrict__ ctx, const float* __restrict__ Wf,
    float* __restrict__ fvec, int bid, int tid)
{
    const int lane = tid & 63;
    const int o = bid * 4 + (tid >> 6);
    const int b = o >> 10, orow = o & 1023;
    const float* x  = ctx + (size_t)b * D_;
    const float* wf = Wf + (size_t)orow * D_;
    float s = 0.f;
#pragma unroll
    for (int it = 0; it < 4; ++it) {
        float4 xv = *(const float4*)(x + it * 256 + lane * 4);
        float4 wv = *(const float4*)(wf + it * 256 + lane * 4);
        s += xv.x * wv.x + xv.y * wv.y + xv.z * wv.z + xv.w * wv.w;
    }
#pragma unroll
    for (int m = 1; m < 64; m <<= 1) s += __shfl_xor(s, m);
    if (lane == 0) fvec[o] = s;
}

__device__ __forceinline__ void ln_body(
    const short* __restrict__ hbm, const float* __restrict__ fvec,
    const float* __restrict__ gamma, const float* __restrict__ beta,
    float* __restrict__ out, float* rs, float* rq, int row, int tid)
{
    const int b = row >> 11;
    const int lane = tid & 63, wave = tid >> 6;

    short4 hv4 = *(const short4*)(hbm + (size_t)row * D_ + tid * 4);
    float4 fv = *(const float4*)(fvec + (size_t)b * D_ + tid * 4);
    const float y0 = bf2f((unsigned short)hv4.x) + fv.x;
    const float y1 = bf2f((unsigned short)hv4.y) + fv.y;
    const float y2 = bf2f((unsigned short)hv4.z) + fv.z;
    const float y3 = bf2f((unsigned short)hv4.w) + fv.w;

    float s = y0 + y1 + y2 + y3;
    float q = y0 * y0 + y1 * y1 + y2 * y2 + y3 * y3;
#pragma unroll
    for (int m = 1; m < 64; m <<= 1) { s += __shfl_xor(s, m); q += __shfl_xor(q, m); }

    if (lane == 0) { rs[wave] = s; rq[wave] = q; }
    __syncthreads();
    s = rs[0] + rs[1] + rs[2] + rs[3];
    q = rq[0] + rq[1] + rq[2] + rq[3];
    __syncthreads();

    const float mu  = s * (1.f / D_);
    const float var = q * (1.f / D_) - mu * mu;
    const float inv = rsqrtf(var + 1e-5f);

    float4 gv = *(const float4*)(gamma + tid * 4);
    float4 bv = *(const float4*)(beta + tid * 4);
    float4 ov;
    ov.x = (y0 - mu) * inv * gv.x + bv.x;
    ov.y = (y1 - mu) * inv * gv.y + bv.y;
    ov.z = (y2 - mu) * inv * gv.z + bv.z;
    ov.w = (y3 - mu) * inv * gv.w + bv.w;
    *(float4*)(out + (size_t)row * D_ + tid * 4) = ov;
}

// ===========================================================================
// Fused cooperative kernel (preferred path)
// ===========================================================================
struct ProjSm { short sA[64 * 32]; short sB[128 * 32]; float part[4][64]; };
struct HbarSm { float smx[8]; float sism[8]; float wl[8][128]; };
struct CtxSm  { float xs[1024]; };
struct LnSm   { float rs[4]; float rq[4]; };
union SmU { ProjSm proj; HbarSm hbar; CtxSm ctx; LnSm ln; };

__global__ __launch_bounds__(256, 4) void k_fused(
    const float* __restrict__ h, const float* __restrict__ Wr,
    const float* __restrict__ att_r, const float* __restrict__ Wf,
    const float* __restrict__ gamma, const float* __restrict__ beta,
    float* __restrict__ out, float* __restrict__ sr, float* __restrict__ hp,
    float* __restrict__ ctx, float* __restrict__ fvec,
    short* __restrict__ hb, short* __restrict__ wrb)
{
    cg::grid_group grid = cg::this_grid();
    __shared__ SmU sm;

    const int tid = threadIdx.x;
    const int bid = blockIdx.x;

    for (int u = bid; u < 4608; u += 1024)
        cvt_unit(h, hb, Wr, wrb, u, tid);
    grid.sync();

    proj_body(hb, wrb, att_r, sr, sm.proj.sA, sm.proj.sB, sm.proj.part,
              (bid & 127) * 64, bid >> 7, tid);
    grid.sync();

    if (bid < 256)
        hbar_body(hb, sr, hp, sm.hbar.smx, sm.hbar.sism, sm.hbar.wl,
                  bid & 3, (bid >> 2) & 15, bid >> 6, tid);
    grid.sync();

    ctx_body(hp, Wr, ctx, sm.ctx.xs, bid, tid);
    grid.sync();

    fvec_body(ctx, Wf, fvec, bid, tid);
    grid.sync();

    for (int r = 0; r < 8; ++r)
        ln_body(hb, fvec, gamma, beta, out, sm.ln.rs, sm.ln.rq,
                bid + r * 1024, tid);
}

// ===========================================================================
// Fallback kernels (R14-proven 6-kernel path)
// ===========================================================================
__global__ __launch_bounds__(256) void k_cvt(
    const float* __restrict__ h, short* __restrict__ hb,
    const float* __restrict__ Wr, short* __restrict__ wrb)
{
    cvt_unit(h, hb, Wr, wrb, blockIdx.x, threadIdx.x);
}

__global__ __launch_bounds__(256) void k_proj_sr(
    const short* __restrict__ hb, const short* __restrict__ wrb,
    const float* __restrict__ att_r, float* __restrict__ sr)
{
    __shared__ ProjSm sm;
    proj_body(hb, wrb, att_r, sr, sm.sA, sm.sB, sm.part,
              blockIdx.x * 64, blockIdx.y, threadIdx.x);
}

__global__ __launch_bounds__(256) void k_hbar(
    const short* __restrict__ hbm, const float* __restrict__ sr,
    float* __restrict__ hp)
{
    __shared__ HbarSm sm;
    hbar_body(hbm, sr, hp, sm.smx, sm.sism, sm.wl,
              blockIdx.x, blockIdx.y, blockIdx.z, threadIdx.x);
}

__global__ __launch_bounds__(256) void k_ctx(
    const float* __restrict__ hp, const float* __restrict__ Wr,
    float* __restrict__ ctx)
{
    __shared__ CtxSm sm;
    ctx_body(hp, Wr, ctx, sm.xs, blockIdx.x, threadIdx.x);
}

__global__ __launch_bounds__(256) void k_fvec(
    const float* __restrict__ ctx, const float* __restrict__ Wf,
    float* __restrict__ fvec)
{
    fvec_body(ctx, Wf, fvec, blockIdx.x, threadIdx.x);
}

__global__ __launch_bounds__(256) void k_ln(
    const short* __restrict__ hbm, const float* __restrict__ fvec,
    const float* __restrict__ gamma, const float* __restrict__ beta,
    float* __restrict__ out)
{
    __shared__ LnSm sm;
    ln_body(hbm, fvec, gamma, beta, out, sm.rs, sm.rq,
            blockIdx.x, threadIdx.x);
}

// ---------------------------------------------------------------------------
extern "C" void kernel_launch(void* const* d_in, const int* in_sizes, int n_in,
                              void* d_out, int out_size, void* d_ws, size_t ws_size,
                              hipStream_t stream) {
    const float* h     = (const float*)d_in[0];
    // d_in[1] = Wl  : dead (softmax over additive scores cancels sl)
    const float* Wr    = (const float*)d_in[2];
    // d_in[3] = att_l : dead
    const float* att_r = (const float*)d_in[4];
    const float* Wf    = (const float*)d_in[5];
    const float* gamma = (const float*)d_in[6];
    const float* beta  = (const float*)d_in[7];
    float* out = (float*)d_out;

    char* ws = (char*)d_ws;
    float* sr    = (float*)(ws);                  // B*H*N      = 256 KB
    float* hp    = (float*)(ws + 524288);         // 2 MB
    float* ctx   = (float*)(ws + 2752512);        // 16 KB
    float* fvec  = (float*)(ws + 2768896);        // 16 KB
    short* hb    = (short*)(ws + 4194304);        // 16 MB bf16 h
    short* wrb   = (short*)(ws + 4194304 + 16777216); // 2 MB bf16 Wr

    void* args[] = {
        (void*)&h, (void*)&Wr, (void*)&att_r, (void*)&Wf,
        (void*)&gamma, (void*)&beta, (void*)&out, (void*)&sr,
        (void*)&hp, (void*)&ctx, (void*)&fvec, (void*)&hb, (void*)&wrb
    };
    hipError_t err = hipLaunchCooperativeKernel(
        (const void*)k_fused, dim3(1024), dim3(256), args, 0, stream);

    if (err != hipSuccess) {
        (void)hipGetLastError();   // clear error state; take fallback path
        k_cvt<<<4096 + 512, 256, 0, stream>>>(h, hb, Wr, wrb);
        k_proj_sr<<<dim3(B_ * N_ / 64, H_), 256, 0, stream>>>(hb, wrb, att_r, sr);
        k_hbar<<<dim3(4, 16, 4), 256, 0, stream>>>(hb, sr, hp);
        k_ctx<<<1024, 256, 0, stream>>>(hp, Wr, ctx);
        k_fvec<<<1024, 256, 0, stream>>>(ctx, Wf, fvec);
        k_ln<<<B_ * N_, 256, 0, stream>>>(hb, fvec, gamma, beta, out);
    }
}

// Round 17
// 78.200 us; speedup vs baseline: 7.5939x; 7.5939x over previous
//
#include <hip/hip_runtime.h>
#include <hip/hip_bf16.h>

#define B_ 4
#define N_ 2048
#define D_ 1024
#define H_ 8
#define HD_ 128

typedef __attribute__((ext_vector_type(4))) float f32x4;
typedef __attribute__((ext_vector_type(8))) short bf16x8;

__device__ __forceinline__ short f2bf(float f) {
    unsigned u = __builtin_bit_cast(unsigned, f);
    u = (u + 0x7FFFu + ((u >> 16) & 1u)) >> 16;   // round-to-nearest-even
    return (short)u;
}
__device__ __forceinline__ float bf2f(unsigned short s) {
    unsigned u = (unsigned)s << 16;
    return __builtin_bit_cast(float, u);
}

typedef const __attribute__((address_space(1))) void* gas_t;
typedef __attribute__((address_space(3))) void* las_t;

__device__ __forceinline__ void gload16(const void* g, void* l) {
    // lane i's 16B from per-lane g -> wave-uniform LDS base + lane*16
    __builtin_amdgcn_global_load_lds((gas_t)g, (las_t)l, 16, 0, 0);
}

// ---------------------------------------------------------------------------
// Kernel 0: fp32 -> bf16 pack for h (4096 blocks) and Wr (512 blocks), fused.
// ---------------------------------------------------------------------------
__global__ __launch_bounds__(256) void k_cvt(
    const float* __restrict__ h, short* __restrict__ hb,
    const float* __restrict__ Wr, short* __restrict__ wrb)
{
    int blk = blockIdx.x;
    const float* src;
    short* dst;
    int i;
    if (blk < 4096) { src = h;  dst = hb;  i = blk * 256 + threadIdx.x; }
    else            { src = Wr; dst = wrb; i = (blk - 4096) * 256 + threadIdx.x; }
    float4 a = ((const float4*)src)[i * 2];
    float4 b = ((const float4*)src)[i * 2 + 1];
    bf16x8 o;
    o[0] = f2bf(a.x); o[1] = f2bf(a.y); o[2] = f2bf(a.z); o[3] = f2bf(a.w);
    o[4] = f2bf(b.x); o[5] = f2bf(b.y); o[6] = f2bf(b.z); o[7] = f2bf(b.w);
    ((bf16x8*)dst)[i] = o;
}

// ---------------------------------------------------------------------------
// Kernel 1: GEMM fr = h @ Wr^T, 64x128 tile (measured-best), BK=32, now
// DOUBLE-BUFFERED 2-phase (T3 minimum recipe at the winning tile size):
//   prologue STAGE(buf0); loop { STAGE(buf^1); compute(buf); ONE barrier; }
// The stage's L2 round-trip overlaps the MFMA phase instead of being
// barrier-drained with nothing in flight (R12's 2-barrier loop).
// Linear LDS is conflict-free at BK=32 (64B row stride = 16-bank offset,
// 2-way = free). Grid = 128 row-tiles x 8 heads = 1024 blocks (4/CU; grid
// is the occupancy cap). Coop-kernel variant measured 594us (grid.sync
// ~110us on 8 XCDs) -- multi-kernel graph path is structurally right.
// Fused epilogue: sr[b,head,j] = sum_c leaky(fr[j, head*128+c]) * att_r[c]
// ---------------------------------------------------------------------------
__global__ __launch_bounds__(256) void k_proj_sr(
    const short* __restrict__ hb, const short* __restrict__ wrb,
    const float* __restrict__ att_r, float* __restrict__ sr)
{
    __shared__ short sA[2][64 * 32];    // 2 x 4 KB
    __shared__ short sB[2][128 * 32];   // 2 x 8 KB
    __shared__ float part[4][64];

    const int tid  = threadIdx.x;
    const int lane = tid & 63;
    const int wave = tid >> 6;         // 0..3 = column group (32 cols each)
    const int cc   = lane & 15;
    const int g    = lane >> 4;
    const int rowBase = blockIdx.x * 64;    // 0..8191 step 64
    const int head    = blockIdx.y;

    const int srow = lane >> 2;                       // 0..15
    const int scol = (lane & 3) * 8;                  // bf16 elems
    const short* gA0 = hb  + (size_t)(rowBase + wave * 16 + srow) * D_ + scol;
    const short* gB0 = wrb + (size_t)(head * HD_ + wave * 32 + srow) * D_ + scol;
    const short* gB1 = gB0 + (size_t)16 * D_;
    const int offA = wave * 1024;      // bytes within a buffer
    const int offB = wave * 2048;

    f32x4 acc[4][2];
#pragma unroll
    for (int m = 0; m < 4; ++m)
#pragma unroll
        for (int n = 0; n < 2; ++n) acc[m][n] = (f32x4){0.f, 0.f, 0.f, 0.f};

    // prologue: stage K-step 0 into buffer 0
    gload16(gA0, (char*)sA[0] + offA);
    gload16(gB0, (char*)sB[0] + offB);
    gload16(gB1, (char*)sB[0] + offB + 1024);
    __syncthreads();

    for (int t = 0; t < 32; ++t) {
        const int cur = t & 1;
        if (t < 31) {
            const int k0 = (t + 1) * 32;
            gload16(gA0 + k0, (char*)sA[cur ^ 1] + offA);
            gload16(gB0 + k0, (char*)sB[cur ^ 1] + offB);
            gload16(gB1 + k0, (char*)sB[cur ^ 1] + offB + 1024);
        }
        const short* bufA = sA[cur];
        const short* bufB = sB[cur];
        bf16x8 aF[4], bF[2];
#pragma unroll
        for (int m = 0; m < 4; ++m)
            aF[m] = *(const bf16x8*)(bufA + (m * 16 + cc) * 32 + g * 8);
#pragma unroll
        for (int n = 0; n < 2; ++n)
            bF[n] = *(const bf16x8*)(bufB + (wave * 32 + n * 16 + cc) * 32 + g * 8);
        __builtin_amdgcn_s_setprio(1);
#pragma unroll
        for (int m = 0; m < 4; ++m)
#pragma unroll
            for (int n = 0; n < 2; ++n)
                acc[m][n] = __builtin_amdgcn_mfma_f32_16x16x32_bf16(
                    aF[m], bF[n], acc[m][n], 0, 0, 0);
        __builtin_amdgcn_s_setprio(0);
        __syncthreads();   // ONE barrier/step: next buf staged + cur reads done
    }

    // Epilogue: row = rowBase + m*16 + g*4 + r, col = wave*32 + n*16 + cc
    float ar[2];
#pragma unroll
    for (int n = 0; n < 2; ++n) ar[n] = att_r[wave * 32 + n * 16 + cc];

#pragma unroll
    for (int m = 0; m < 4; ++m) {
#pragma unroll
        for (int r = 0; r < 4; ++r) {
            float p = 0.f;
#pragma unroll
            for (int n = 0; n < 2; ++n) {
                float v = acc[m][n][r];
                v = v > 0.f ? v : 0.01f * v;    // leaky
                p += v * ar[n];
            }
            p += __shfl_xor(p, 1); p += __shfl_xor(p, 2);
            p += __shfl_xor(p, 4); p += __shfl_xor(p, 8);
            if (cc == 0) part[wave][m * 16 + g * 4 + r] = p;
        }
    }
    __syncthreads();
    if (tid < 64) {
        const int grow = rowBase + tid;
        const int b = grow >> 11, j = grow & (N_ - 1);
        sr[(size_t)(b * H_ + head) * N_ + j] =
            part[0][tid] + part[1][tid] + part[2][tid] + part[3][tid];
    }
}

// ---------------------------------------------------------------------------
// Kernel 2: hbar partials with inline softmax stats (L2-resident sr).
//   hp[jc*32 + b*8 + h][d] = sum_{j in chunk jc} exp(sr-mx)/sum * hb[b,j,d]
// Grid dim3(4 dc, 16 jc, 4 b) = 256 blocks. jj-loop unrolled x4 so 4 row
// loads are in flight (1 block/CU -> latency-sensitive).
// ---------------------------------------------------------------------------
__global__ __launch_bounds__(256) void k_hbar(
    const short* __restrict__ hbm, const float* __restrict__ sr,
    float* __restrict__ hp)
{
    const int dc = blockIdx.x;   // 0..3
    const int jc = blockIdx.y;   // 0..15  (128 j each)
    const int b  = blockIdx.z;   // 0..3
    const int tid = threadIdx.x;
    const int d = dc * 256 + tid;

    __shared__ float smx[8], sism[8];
    {
        const int hh = tid >> 5;
        const int sl = tid & 31;
        const float4* row = (const float4*)(sr + (size_t)(b * H_ + hh) * N_);
        float4 v[16];
        float mx = -1e30f;
#pragma unroll
        for (int k = 0; k < 16; ++k) {
            v[k] = row[sl + k * 32];
            mx = fmaxf(fmaxf(mx, fmaxf(v[k].x, v[k].y)), fmaxf(v[k].z, v[k].w));
        }
#pragma unroll
        for (int m = 1; m < 32; m <<= 1) mx = fmaxf(mx, __shfl_xor(mx, m));
        float sum = 0.f;
#pragma unroll
        for (int k = 0; k < 16; ++k)
            sum += expf(v[k].x - mx) + expf(v[k].y - mx) +
                   expf(v[k].z - mx) + expf(v[k].w - mx);
#pragma unroll
        for (int m = 1; m < 32; m <<= 1) sum += __shfl_xor(sum, m);
        if (sl == 0) { smx[hh] = mx; sism[hh] = 1.f / sum; }
    }
    __syncthreads();

    __shared__ float wl[8][128];
    for (int idx = tid; idx < 1024; idx += 256) {
        const int hh = idx >> 7, jj = idx & 127;
        wl[hh][jj] = expf(sr[(size_t)(b * H_ + hh) * N_ + jc * 128 + jj]
                          - smx[hh]) * sism[hh];
    }
    __syncthreads();

    float acc[8] = {0.f, 0.f, 0.f, 0.f, 0.f, 0.f, 0.f, 0.f};
    const short* hp0 = hbm + ((size_t)(b * N_ + jc * 128)) * D_ + d;
#pragma unroll 4
    for (int jj = 0; jj < 128; ++jj) {
        float hv = bf2f((unsigned short)hp0[(size_t)jj * D_]);
#pragma unroll
        for (int hh = 0; hh < 8; ++hh) acc[hh] += wl[hh][jj] * hv;
    }
#pragma unroll
    for (int hh = 0; hh < 8; ++hh)
        hp[((size_t)(jc * 32) + b * 8 + hh) * D_ + d] = acc[hh];
}

// ---------------------------------------------------------------------------
// Kernel 3: fused hp-reduce + ctx. 1024 blocks; block (bh, dg) reduces its
// (b,head) panel from hp into LDS (L2-resident) then computes 4 ctx outputs
// (one per wave) with coalesced Wr rows.
// ---------------------------------------------------------------------------
__global__ __launch_bounds__(256) void k_ctx(
    const float* __restrict__ hp, const float* __restrict__ Wr,
    float* __restrict__ ctx)
{
    const int bh = blockIdx.x >> 5;           // 0..31 = b*8 + head
    const int b = bh >> 3, head = bh & 7;
    const int dg = (blockIdx.x & 31) * 4;     // 4 outputs per block
    const int tid = threadIdx.x;
    const int lane = tid & 63, wave = tid >> 6;

    __shared__ float xs[1024];
    float4 s = {0.f, 0.f, 0.f, 0.f};
#pragma unroll
    for (int jc = 0; jc < 16; ++jc) {
        float4 v = ((const float4*)(hp + ((size_t)(jc * 32) + bh) * D_))[tid];
        s.x += v.x; s.y += v.y; s.z += v.z; s.w += v.w;
    }
    ((float4*)xs)[tid] = s;
    __syncthreads();

    const int o = dg + wave;                 // d' within head (0..127)
    const float* wrow = Wr + (size_t)(head * HD_ + o) * D_;
    float acc = 0.f;
#pragma unroll
    for (int it = 0; it < 4; ++it) {
        float4 wv = *(const float4*)(wrow + it * 256 + lane * 4);
        float4 xv = ((const float4*)xs)[it * 64 + lane];
        acc += wv.x * xv.x + wv.y * xv.y + wv.z * xv.z + wv.w * xv.w;
    }
#pragma unroll
    for (int m = 1; m < 64; m <<= 1) acc += __shfl_xor(acc, m);
    if (lane == 0) ctx[(size_t)b * D_ + head * HD_ + o] = acc;
}

// ---------------------------------------------------------------------------
// Kernel 4: fvec[b, o] = sum_e ctx[b,e] * Wf[o,e]  (1024 blocks)
// ---------------------------------------------------------------------------
__global__ __launch_bounds__(256) void k_fvec(
    const float* __restrict__ ctx, const float* __restrict__ Wf,
    float* __restrict__ fvec)
{
    const int o = blockIdx.x * 4 + (threadIdx.x >> 6);   // 0..4095
    const int lane = threadIdx.x & 63;
    const int b = o >> 10, orow = o & 1023;
    const float* x  = ctx + (size_t)b * D_;
    const float* wf = Wf + (size_t)orow * D_;
    float s = 0.f;
#pragma unroll
    for (int it = 0; it < 4; ++it) {
        float4 xv = *(const float4*)(x + it * 256 + lane * 4);
        float4 wv = *(const float4*)(wf + it * 256 + lane * 4);
        s += xv.x * wv.x + xv.y * wv.y + xv.z * wv.z + xv.w * wv.w;
    }
#pragma unroll
    for (int m = 1; m < 64; m <<= 1) s += __shfl_xor(s, m);
    if (lane == 0) fvec[o] = s;
}

// ---------------------------------------------------------------------------
// Kernel 5: out = LayerNorm(hb + fvec[b]) * gamma + beta, one block per row.
// Reads the bf16 copy of h (half the fetch; |err| <= 2^-9|h| ~ 0.008 vs
// threshold 0.1075).
// ---------------------------------------------------------------------------
__global__ __launch_bounds__(256) void k_ln(
    const short* __restrict__ hbm, const float* __restrict__ fvec,
    const float* __restrict__ gamma, const float* __restrict__ beta,
    float* __restrict__ out)
{
    const int row = blockIdx.x;
    const int b = row >> 11;
    const int tid = threadIdx.x;
    const int lane = tid & 63, wave = tid >> 6;

    short4 hv4 = *(const short4*)(hbm + (size_t)row * D_ + tid * 4);
    float4 fv = *(const float4*)(fvec + (size_t)b * D_ + tid * 4);
    const float y0 = bf2f((unsigned short)hv4.x) + fv.x;
    const float y1 = bf2f((unsigned short)hv4.y) + fv.y;
    const float y2 = bf2f((unsigned short)hv4.z) + fv.z;
    const float y3 = bf2f((unsigned short)hv4.w) + fv.w;

    float s = y0 + y1 + y2 + y3;
    float q = y0 * y0 + y1 * y1 + y2 * y2 + y3 * y3;
#pragma unroll
    for (int m = 1; m < 64; m <<= 1) { s += __shfl_xor(s, m); q += __shfl_xor(q, m); }

    __shared__ float rs[4], rq[4];
    if (lane == 0) { rs[wave] = s; rq[wave] = q; }
    __syncthreads();
    s = rs[0] + rs[1] + rs[2] + rs[3];
    q = rq[0] + rq[1] + rq[2] + rq[3];

    const float mu  = s * (1.f / D_);
    const float var = q * (1.f / D_) - mu * mu;
    const float inv = rsqrtf(var + 1e-5f);

    float4 gv = *(const float4*)(gamma + tid * 4);
    float4 bv = *(const float4*)(beta + tid * 4);
    float4 ov;
    ov.x = (y0 - mu) * inv * gv.x + bv.x;
    ov.y = (y1 - mu) * inv * gv.y + bv.y;
    ov.z = (y2 - mu) * inv * gv.z + bv.z;
    ov.w = (y3 - mu) * inv * gv.w + bv.w;
    *(float4*)(out + (size_t)row * D_ + tid * 4) = ov;
}

// ---------------------------------------------------------------------------
extern "C" void kernel_launch(void* const* d_in, const int* in_sizes, int n_in,
                              void* d_out, int out_size, void* d_ws, size_t ws_size,
                              hipStream_t stream) {
    const float* h     = (const float*)d_in[0];
    // d_in[1] = Wl  : dead (softmax over additive scores cancels sl)
    const float* Wr    = (const float*)d_in[2];
    // d_in[3] = att_l : dead
    const float* att_r = (const float*)d_in[4];
    const float* Wf    = (const float*)d_in[5];
    const float* gamma = (const float*)d_in[6];
    const float* beta  = (const float*)d_in[7];
    float* out = (float*)d_out;

    char* ws = (char*)d_ws;
    float* sr    = (float*)(ws);                  // B*H*N      = 256 KB
    float* hp    = (float*)(ws + 524288);         // 2 MB
    float* ctx   = (float*)(ws + 2752512);        // 16 KB
    float* fvec  = (float*)(ws + 2768896);        // 16 KB
    short* hb    = (short*)(ws + 4194304);        // 16 MB bf16 h
    short* wrb   = (short*)(ws + 4194304 + 16777216); // 2 MB bf16 Wr

    k_cvt<<<4096 + 512, 256, 0, stream>>>(h, hb, Wr, wrb);
    k_proj_sr<<<dim3(B_ * N_ / 64, H_), 256, 0, stream>>>(hb, wrb, att_r, sr);
    k_hbar<<<dim3(4, 16, 4), 256, 0, stream>>>(hb, sr, hp);
    k_ctx<<<1024, 256, 0, stream>>>(hp, Wr, ctx);
    k_fvec<<<1024, 256, 0, stream>>>(ctx, Wf, fvec);
    k_ln<<<B_ * N_, 256, 0, stream>>>(hb, fvec, gamma, beta, out);
}